// Round 13
// baseline (1284.337 us; speedup 1.0000x reference)
//
#include <hip/hip_runtime.h>
#include <stdint.h>

typedef unsigned long long u64;
typedef unsigned int u32;
typedef unsigned short u16;

#define BATCH 64
#define NN    512
#define NAUG  1024
#define DM    256
#define NEDGE 4096
#define CAP   64
#define PK2   32       // packed entry-pair slots = CAP/2 (written)
#define PK2A  36       // allocated slots (pad stays zero -> unguarded preload)
#define LM    128      // Lanczos steps (96 under-converged: R9 absmax 0.342)

// ---------------- workspace layout (bytes) ----------------
#define OFF_ADJ   ((size_t)0)
#define SZ_ADJ    ((size_t)BATCH*NN*8*8)                 // 2 MiB bitmask
#define OFF_ADJT  (OFF_ADJ + SZ_ADJ)
#define OFF_LAM   (OFF_ADJT + SZ_ADJ)                    // 4B lambda
#define OFF_LMX   (OFF_LAM + 64)                         // int lmax[64]
#define OFF_PK2   (OFF_LAM + 1024)
#define SZ_PK2    ((size_t)BATCH*PK2A*NN*16)             // 18.9 MB packed-pair lap stream
#define OFF_DEGI  (OFF_PK2 + SZ_PK2)
#define OFF_LENS  (OFF_DEGI + (size_t)BATCH*NN*4)
#define OFF_ENTS  (OFF_LENS + (size_t)BATCH*NN*4)
#define OFF_VALS  (OFF_ENTS + (size_t)BATCH*NN*CAP*4)
#define OFF_XF    (OFF_VALS + (size_t)BATCH*NN*CAP*4)    // x fp32 [b,1024,256]
#define OFF_XT1   (OFF_XF  + (size_t)BATCH*NAUG*DM*4)    // t1@x fp32
#define OFF_S     (OFF_XT1 + (size_t)BATCH*NAUG*DM*4)    // xf2 ping-pong (was sBuf)

// ---------------- adjacency scatter (bitmask) ----------------
__global__ void k_scatter(const int* __restrict__ senders, const int* __restrict__ receivers,
                          u64* __restrict__ adj, u64* __restrict__ adjT){
    int idx = blockIdx.x * 256 + threadIdx.x;          // BATCH*NEDGE threads
    int b = idx >> 12;
    int s = senders[idx];
    int r = receivers[idx];
    if (s >= 0){
        atomicOr(&adj [((size_t)b*NN + s)*8 + (r >> 6)], 1ull << (r & 63));
        atomicOr(&adjT[((size_t)b*NN + r)*8 + (s >> 6)], 1ull << (s & 63));
    }
}

// ---------------- degree (exact double 1/sqrt) ----------------
__global__ void k_deg(const u64* __restrict__ adj, const u64* __restrict__ adjT,
                      float* __restrict__ degInv){
    int idx = blockIdx.x * 256 + threadIdx.x;          // BATCH*NN threads
    const u64* a = adj  + (size_t)idx * 8;
    const u64* t = adjT + (size_t)idx * 8;
    int deg = 0;
#pragma unroll
    for (int w = 0; w < 8; ++w) deg += __popcll(a[w] | t[w]);
    degInv[idx] = (float)(1.0 / sqrt((double)(deg < 1 ? 1 : deg)));
}

// ---------------- build CSR + packed-pair stream (one wave per row) ----------
__global__ __launch_bounds__(256)
void k_build(const u64* __restrict__ adj, const u64* __restrict__ adjT,
             const float* __restrict__ degInv, const int* __restrict__ n_node,
             u32* __restrict__ ents, float* __restrict__ vals, int* __restrict__ lens,
             uint2* __restrict__ pk2, int* __restrict__ lmax){
    int gw   = (blockIdx.x * 256 + threadIdx.x) >> 6;  // global wave = row id
    int lane = threadIdx.x & 63;
    int b = gw >> 9;
    int i = gw & (NN - 1);
    const u64* arow = adj  + ((size_t)b*NN + i)*8;
    const u64* trow = adjT + ((size_t)b*NN + i)*8;
    int wsel = lane >> 3, sh = (lane & 7) * 8;
    u32 ba = (u32)((arow[wsel] >> sh) & 0xFFull);
    u32 bt = (u32)((trow[wsel] >> sh) & 0xFFull);
    int nn_b = n_node[b];
    bool mi  = i < nn_b;
    float di = degInv[b*NN + i];
    int j0 = lane * 8;

    float vr_[8], vi_[8];
    int cnt = 0;
#pragma unroll
    for (int jj = 0; jj < 8; ++jj){
        int j = j0 + jj;
        int a = (ba >> jj) & 1, t = (bt >> jj) & 1;
        bool mm = mi && (j < nn_b);
        float c = di * degInv[b*NN + j];
        float vr = 0.f, vi = 0.f;
        if (j == i){
            if (mm) vr = 1.0f - (a ? c : 0.0f);        // diag: mask*(1 - selfloop*c)
        } else if (mm && ((a | t) != 0)){
            if (a & t)      vr = -c;                   // lap = -c
            else if (a)     vi = -c;                   // lap = -i*c
            else            vi =  c;                   // lap = +i*c
        }
        vr_[jj] = vr; vi_[jj] = vi;
        cnt += (vr != 0.f || vi != 0.f) ? 1 : 0;
    }
    // wave-wide exclusive scan of cnt
    int off = cnt;
#pragma unroll
    for (int d = 1; d < 64; d <<= 1){
        int nb = __shfl_up(off, d);
        if (lane >= d) off += nb;
    }
    int excl = off - cnt;
    int tot  = __shfl(off, 63);
    int p = excl;
    u32*   erow = ents + ((size_t)b*NN + i)*CAP;
    float* vrow = vals + ((size_t)b*NN + i)*CAP;
#pragma unroll
    for (int jj = 0; jj < 8; ++jj){
        float vr = vr_[jj], vi = vi_[jj];
        if (vr != 0.f || vi != 0.f){
            if (p < CAP){
                int ty = (vi != 0.f) ? 1 : 0;
                int j = j0 + jj;
                float v = ty ? vi : vr;
                erow[p] = (u32)j | ((u32)ty << 9);
                vrow[p] = v;
                size_t slot = ((size_t)b*PK2A + (p >> 1))*NN + i;
                pk2[slot*2 + (p & 1)] =
                    make_uint2((u32)((j << 3) + (ty << 12)), __float_as_uint(v));
            }
            p++;
        }
    }
    if (lane == 63){
        int tc = tot > CAP ? CAP : tot;
        lens[b*NN + i] = tc;
        atomicMax(&lmax[b], tc);
    }
}

// ---------------- Lanczos: 8 waves/graph; SORTED row->lane assignment ----------
// (R16 version — verified passing; k_lanczos <247us after the sort.)
#define DO_G4(S0)                                                         \
    {                                                                     \
        float2 vva = VALS[S0][tid];                                       \
        float2 vvb = VALS[S0+1][tid];                                     \
        u32 opa = offp[S0], opb = offp[S0+1];                             \
        float2 u0 = *(const float2*)((const char*)XY + (opa & 0xFFFFu));  \
        float2 u1 = *(const float2*)((const char*)XY + (opa >> 16));      \
        float2 u2 = *(const float2*)((const char*)XY + (opb & 0xFFFFu));  \
        float2 u3 = *(const float2*)((const char*)XY + (opb >> 16));      \
        wr0 = fmaf(vva.x, u0.x, wr0); wi0 = fmaf(vva.x, u0.y, wi0);       \
        wr0 = fmaf(vva.y, u1.x, wr0); wi0 = fmaf(vva.y, u1.y, wi0);       \
        wr1 = fmaf(vvb.x, u2.x, wr1); wi1 = fmaf(vvb.x, u2.y, wi1);       \
        wr1 = fmaf(vvb.y, u3.x, wr1); wi1 = fmaf(vvb.y, u3.y, wi1);       \
        float2 vvc = VALS[S0+2][tid];                                     \
        float2 vvd = VALS[S0+3][tid];                                     \
        u32 opc = offp[S0+2], opd = offp[S0+3];                           \
        float2 u4 = *(const float2*)((const char*)XY + (opc & 0xFFFFu));  \
        float2 u5 = *(const float2*)((const char*)XY + (opc >> 16));      \
        float2 u6 = *(const float2*)((const char*)XY + (opd & 0xFFFFu));  \
        float2 u7 = *(const float2*)((const char*)XY + (opd >> 16));      \
        wr0 = fmaf(vvc.x, u4.x, wr0); wi0 = fmaf(vvc.x, u4.y, wi0);       \
        wr0 = fmaf(vvc.y, u5.x, wr0); wi0 = fmaf(vvc.y, u5.y, wi0);       \
        wr1 = fmaf(vvd.x, u6.x, wr1); wi1 = fmaf(vvd.x, u6.y, wi1);       \
        wr1 = fmaf(vvd.y, u7.x, wr1); wi1 = fmaf(vvd.y, u7.y, wi1);       \
    }

__global__ __launch_bounds__(512)
void k_lanczos(const uint4* __restrict__ pk2, const int* __restrict__ lens,
               float* __restrict__ lam){
    int b = blockIdx.x;
    int tid = threadIdx.x;
    int w = tid >> 6, l = tid & 63;
    __shared__ float2 XY[2*NN];                        // 8 KiB: X then Y
    __shared__ float2 VALS[PK2][NN];                   // 128 KiB: [slot][sorted-tid]
    __shared__ float alphS[LM], betS[LM];
    __shared__ float redA[8], redB[8];
    __shared__ int bCnt[PK2 + 1], bOff[PK2 + 1];       // ES buckets 0..32
    __shared__ u16 sortRow[NN];
    const uint4* base = pk2 + (size_t)b*PK2A*NN;

    // ---- counting sort: lane tid <- tid-th largest-ES row ----
    if (tid <= PK2) bCnt[tid] = 0;
    __syncthreads();
    int defES = (lens[b*NN + tid] + 1) >> 1;           // 0..32
    atomicAdd(&bCnt[defES], 1);
    __syncthreads();
    if (tid == 0){
        int acc = 0;
        for (int e = PK2; e >= 0; --e){ bOff[e] = acc; acc += bCnt[e]; }
    }
    __syncthreads();
    int pos = atomicAdd(&bOff[defES], 1);
    sortRow[pos] = (u16)tid;                           // thread at pos handles row tid
    __syncthreads();
    int row  = sortRow[tid];                           // my actual row
    int myES = (lens[b*NN + row] + 1) >> 1;

    // ---- preload: offsets packed into 32 regs, values staged to LDS ----
    u32 offp[PK2];
#pragma unroll
    for (int s = 0; s < PK2; ++s){
        uint4 q = base[(size_t)s*NN + row];
        offp[s] = (q.x & 0xFFFFu) | (q.z << 16);       // byteoff <= 8184, fits 13b
        VALS[s][tid] = make_float2(__uint_as_float(q.y), __uint_as_float(q.w));
    }

    u32 h = (u32)row * 2654435761u + 0x9E3779B9u;
    h ^= h >> 16; h *= 0x85EBCA6Bu; h ^= h >> 13;
    float xr = (float)(h & 0xFFFF) * (1.f/65536.f) - 0.5f;
    h = h * 1664525u + 1013904223u;
    float xi = (float)(h & 0xFFFF) * (1.f/65536.f) - 0.5f;
    float ss = xr*xr + xi*xi;
#pragma unroll
    for (int d = 1; d < 64; d <<= 1) ss += __shfl_xor(ss, d);
    if (l == 0) redA[w] = ss;
    __syncthreads();
    float inv0 = 1.f / sqrtf(redA[0] + redA[1] + redA[2] + redA[3]
                           + redA[4] + redA[5] + redA[6] + redA[7]);
    xr *= inv0; xi *= inv0;
    XY[row]      = make_float2(xr, xi);
    XY[NN + row] = make_float2(-xi, xr);
    __syncthreads();
    float v0r = 0.f, v0i = 0.f;
    float betaPrev = 0.f;
    int mEff = LM;
    for (int j = 0; j < LM; ++j){
        float wr0 = 0.f, wi0 = 0.f, wr1 = 0.f, wi1 = 0.f;
        if (myES >  0) DO_G4(0);
        if (myES >  4) DO_G4(4);
        if (myES >  8) DO_G4(8);
        if (myES > 12) DO_G4(12);
        if (myES > 16) DO_G4(16);
        if (myES > 20) DO_G4(20);
        if (myES > 24) DO_G4(24);
        if (myES > 28) DO_G4(28);
        float wr = wr0 + wr1, wi = wi0 + wi1;
        // alpha = Re<v1, w> : in-wave butterfly, then 8-way cross-wave via LDS
        float pa = xr*wr + xi*wi;
#pragma unroll
        for (int d = 1; d < 64; d <<= 1) pa += __shfl_xor(pa, d);
        if (l == 0) redA[w] = pa;
        __syncthreads();
        float paF = redA[0] + redA[1] + redA[2] + redA[3]
                  + redA[4] + redA[5] + redA[6] + redA[7];
        // w -= alpha*v1 + betaPrev*v0 ; beta = ||w|| (explicit, stable)
        wr -= paF*xr + betaPrev*v0r;
        wi -= paF*xi + betaPrev*v0i;
        float pb = wr*wr + wi*wi;
#pragma unroll
        for (int d = 1; d < 64; d <<= 1) pb += __shfl_xor(pb, d);
        if (l == 0) redB[w] = pb;
        __syncthreads();
        float pbF = redB[0] + redB[1] + redB[2] + redB[3]
                  + redB[4] + redB[5] + redB[6] + redB[7];
        float bta = sqrtf(pbF);
        if (w == 0 && l == 0){ alphS[j] = paF; betS[j] = bta; }
        if (pbF < 1e-14f){ mEff = j + 1; break; }      // uniform: pbF same all waves
        float binv = 1.f / bta;
        float nr = wr * binv;
        float ni = wi * binv;
        v0r = xr; v0i = xi;
        xr = nr; xi = ni;
        XY[row]      = make_float2(nr, ni);
        XY[NN + row] = make_float2(-ni, nr);
        __syncthreads();                               // X visible before next e-loop
        betaPrev = bta;
    }
    // parallel-midpoint Sturm bisection on wave 0: lane l tests mid_l; ballot.
    if (w == 0){
        int m = mEff;
        double lo = -0.5, hi = 2.5;                    // lap spectrum in [0,2]
        for (int sweep = 0; sweep < 5; ++sweep){
            double wd = (hi - lo) * (1.0/65.0);
            double mid = lo + wd * (double)(l + 1);
            int cnt = 0;
            double d = (double)alphS[0] - mid;
            if (d < 0.0) cnt++;
            for (int k = 1; k < m; ++k){
                if (d == 0.0) d = -1e-300;
                double bk = (double)betS[k-1];
                d = ((double)alphS[k] - mid) - bk*bk/d;
                if (d < 0.0) cnt++;
            }
            u64 mask = __ballot(cnt >= m);             // mid above lam_max
            if (mask == 0ull){
                lo = lo + wd * 64.0;
            } else {
                int L = __ffsll(mask) - 1;
                hi = lo + wd * (double)(L + 1);
                lo = lo + wd * (double)L;
            }
        }
        if (l == 0){
            float l1 = (float)hi;
            if (l1 < 0.f) l1 = 0.f;
            if (l1 > 2.0f) l1 = 2.0f;                  // normalized-lap bound
            atomicMax((u32*)lam, __float_as_uint(l1));
        }
    }
}

// ---------------- prep: xf = [nodes; 0] fp32 aug-node-major ----------------
__global__ void k_prep32(const float* __restrict__ nodes, float* __restrict__ xf){
    int row = blockIdx.x;                      // b*NAUG + i, 65536 blocks
    int t = threadIdx.x;
    int b = row >> 10, i = row & (NAUG - 1);
    float v = (i < NN) ? nodes[((size_t)b*NN + i)*DM + t] : 0.f;
    xf[(size_t)row*DM + t] = v;
}

// ---------------- SpMM: xt1 = (2/lam)*(lap @ x) - x, fp64 accum ----------------
// R22: old spmm = 1 row/block, len~4-20 SERIAL entries, each er->gather->fma
// chain exposing ~500cy L2/L3 latency -> est ~140us/dispatch (the round-over-
// round ~280us unaccounted budget). Now 8 rows/block with the entry loop
// interleaved across rows: up to 16 independent gathers in flight per
// iteration; `e < len[r]` guards are block-uniform scalar branches (no traffic
// when skipped). Per-row entry ORDER and fp64 fma chain unchanged ->
// BIT-IDENTICAL output.
__global__ __launch_bounds__(256)
void k_spmm(const u32* __restrict__ ents, const float* __restrict__ vals,
            const int* __restrict__ lens, const float* __restrict__ xf,
            const float* __restrict__ lam, float* __restrict__ xt1){
    int i0 = blockIdx.x * 8;                   // 8 rows per block
    int b = blockIdx.y;
    int t = threadIdx.x;
    const float* xb = xf + (size_t)b*NAUG*DM;
    int len[8];
#pragma unroll
    for (int r = 0; r < 8; ++r) len[r] = lens[b*NN + i0 + r];
    int maxl = 0;
#pragma unroll
    for (int r = 0; r < 8; ++r) maxl = len[r] > maxl ? len[r] : maxl;
    double ar[8], ai[8];
#pragma unroll
    for (int r = 0; r < 8; ++r){ ar[r] = 0.0; ai[r] = 0.0; }
    const u32*   erb = ents + ((size_t)b*NN + i0)*CAP;
    const float* evb = vals + ((size_t)b*NN + i0)*CAP;
    for (int e = 0; e < maxl; ++e){
#pragma unroll
        for (int r = 0; r < 8; ++r){
            if (e < len[r]){
                u32 en = erb[r*CAP + e];
                double v = (double)evb[r*CAP + e];
                int j = en & 511;
                double xr = (double)xb[(size_t)j*DM + t];
                double xi = (double)xb[(size_t)(NN + j)*DM + t];
                if (en & 512u){ ar[r] = fma(v, -xi, ar[r]); ai[r] = fma(v, xr, ai[r]); }
                else          { ar[r] = fma(v,  xr, ar[r]); ai[r] = fma(v, xi, ai[r]); }
            }
        }
    }
    double alpha = 2.0 / (double)lam[0];
#pragma unroll
    for (int r = 0; r < 8; ++r){
        size_t ro = ((size_t)b*NAUG + i0 + r)*DM + t;
        size_t io = ((size_t)b*NAUG + NN + i0 + r)*DM + t;
        xt1[ro] = (float)(alpha*ar[r] - (double)xf[ro]);
        xt1[io] = (float)(alpha*ai[r] - (double)xf[io]);
    }
}

// ---------------- fused GEMM+crelu: dst = crelu(x@w0 + xt1@w1 + bias) --------
// (R21 version — verified passing; gemm 245.6us, VGPR 48, occ 50%.)
__global__ __launch_bounds__(256)
void k_gemm32(const float* __restrict__ A0, const float* __restrict__ xt1,
              const float* __restrict__ w0, const float* __restrict__ w1,
              const float* __restrict__ bias, float* __restrict__ dst,
              int rowStride, int imagOff){
    __shared__ float As[32][68];
    __shared__ float Bs[32][68];
    int by = blockIdx.y;
    int b  = by >> 4;
    int i0 = (by & 15) * 32;                   // 32 node-ids per tile
    int n0 = blockIdx.x * 64;
    int tid = threadIdx.x;
    int tx = tid & 15, ty = tid >> 4;
    size_t abase = (size_t)b*NAUG*DM;
    double acc[4][4];
#pragma unroll
    for (int r = 0; r < 4; ++r)
#pragma unroll
        for (int c = 0; c < 4; ++c) acc[r][c] = 0.0;
    for (int ph = 0; ph < 2; ++ph){
        const float* A = ph ? xt1 : A0;
        const float* W = ph ? w1 : w0;
        for (int k0 = 0; k0 < DM; k0 += 32){
#pragma unroll
            for (int l = 0; l < 2; ++l){
                int fi = tid + l*256;          // 512 float4 slots each
                int m  = fi >> 3, c4 = fi & 7; // A: 64 tile-rows x 8 f4
                size_t grow = abase + (size_t)((m & 1)*NN + i0 + (m >> 1))*DM;
                float4 g = *(const float4*)(A + grow + k0 + c4*4);
                As[c4*4+0][m] = g.x; As[c4*4+1][m] = g.y;
                As[c4*4+2][m] = g.z; As[c4*4+3][m] = g.w;
                int kk = fi >> 4, n4 = fi & 15;// B: 32 k x 16 f4
                float4 hh = *(const float4*)(W + ((size_t)(k0 + kk))*DM + n0 + n4*4);
                *(float4*)&Bs[kk][n4*4] = hh;
            }
            __syncthreads();
            float facc[4][4];
#pragma unroll
            for (int r = 0; r < 4; ++r)
#pragma unroll
                for (int c = 0; c < 4; ++c) facc[r][c] = 0.f;
#pragma unroll
            for (int kk = 0; kk < 32; ++kk){
                float4 a4 = *(const float4*)&As[kk][ty*4];
                float4 b4 = *(const float4*)&Bs[kk][tx*4];
                facc[0][0] = fmaf(a4.x, b4.x, facc[0][0]);
                facc[0][1] = fmaf(a4.x, b4.y, facc[0][1]);
                facc[0][2] = fmaf(a4.x, b4.z, facc[0][2]);
                facc[0][3] = fmaf(a4.x, b4.w, facc[0][3]);
                facc[1][0] = fmaf(a4.y, b4.x, facc[1][0]);
                facc[1][1] = fmaf(a4.y, b4.y, facc[1][1]);
                facc[1][2] = fmaf(a4.y, b4.z, facc[1][2]);
                facc[1][3] = fmaf(a4.y, b4.w, facc[1][3]);
                facc[2][0] = fmaf(a4.z, b4.x, facc[2][0]);
                facc[2][1] = fmaf(a4.z, b4.y, facc[2][1]);
                facc[2][2] = fmaf(a4.z, b4.z, facc[2][2]);
                facc[2][3] = fmaf(a4.z, b4.w, facc[2][3]);
                facc[3][0] = fmaf(a4.w, b4.x, facc[3][0]);
                facc[3][1] = fmaf(a4.w, b4.y, facc[3][1]);
                facc[3][2] = fmaf(a4.w, b4.z, facc[3][2]);
                facc[3][3] = fmaf(a4.w, b4.w, facc[3][3]);
            }
#pragma unroll
            for (int r = 0; r < 4; ++r)
#pragma unroll
                for (int c = 0; c < 4; ++c) acc[r][c] += (double)facc[r][c];
            __syncthreads();
        }
    }
    // ---- epilogue: +bias, thread-local crelu on (re,im) row pairs, store ----
    float4 bi = *(const float4*)(bias + n0 + tx*4);
    float* outb = dst + (size_t)b*NAUG*DM;
#pragma unroll
    for (int q = 0; q < 2; ++q){
        float4 re, im;
        re.x = (float)(acc[q*2][0]   + (double)bi.x);
        re.y = (float)(acc[q*2][1]   + (double)bi.y);
        re.z = (float)(acc[q*2][2]   + (double)bi.z);
        re.w = (float)(acc[q*2][3]   + (double)bi.w);
        im.x = (float)(acc[q*2+1][0] + (double)bi.x);
        im.y = (float)(acc[q*2+1][1] + (double)bi.y);
        im.z = (float)(acc[q*2+1][2] + (double)bi.z);
        im.w = (float)(acc[q*2+1][3] + (double)bi.w);
        float4 gr, gi;
        gr.x = (re.x >= 0.f) ? re.x : 0.f;  gi.x = (re.x >= 0.f) ? im.x : 0.f;
        gr.y = (re.y >= 0.f) ? re.y : 0.f;  gi.y = (re.y >= 0.f) ? im.y : 0.f;
        gr.z = (re.z >= 0.f) ? re.z : 0.f;  gi.z = (re.z >= 0.f) ? im.z : 0.f;
        gr.w = (re.w >= 0.f) ? re.w : 0.f;  gi.w = (re.w >= 0.f) ? im.w : 0.f;
        int i = i0 + ty*2 + q;                 // node id for this pair
        float* pre = outb + (size_t)i*rowStride + n0 + tx*4;
        *(float4*)pre            = gr;
        *(float4*)(pre + imagOff) = gi;
    }
}

// ---------------- host launch ----------------
extern "C" void kernel_launch(void* const* d_in, const int* in_sizes, int n_in,
                              void* d_out, int out_size, void* d_ws, size_t ws_size,
                              hipStream_t stream){
    const float* nodes   = (const float*)d_in[0];
    const int*   senders = (const int*)  d_in[1];
    const int*   recvs   = (const int*)  d_in[2];
    const int*   n_node  = (const int*)  d_in[3];
    const float* w00     = (const float*)d_in[4];
    const float* b00     = (const float*)d_in[5];
    const float* w10     = (const float*)d_in[6];
    const float* w01     = (const float*)d_in[7];
    const float* b01     = (const float*)d_in[8];
    const float* w11     = (const float*)d_in[9];
    char* ws = (char*)d_ws;
    u64*   adj    = (u64*)  (ws + OFF_ADJ);
    u64*   adjT   = (u64*)  (ws + OFF_ADJT);
    float* lam    = (float*)(ws + OFF_LAM);
    int*   lmax   = (int*)  (ws + OFF_LMX);
    uint2* pk2    = (uint2*)(ws + OFF_PK2);
    float* degInv = (float*)(ws + OFF_DEGI);
    int*   lens   = (int*)  (ws + OFF_LENS);
    u32*   ents   = (u32*)  (ws + OFF_ENTS);
    float* vals   = (float*)(ws + OFF_VALS);
    float* xf     = (float*)(ws + OFF_XF);
    float* xt1    = (float*)(ws + OFF_XT1);
    float* xf2    = (float*)(ws + OFF_S);      // ping-pong layer-0 output
    float* out    = (float*)d_out;

    // zero adj bitmasks + lambda/lmax + pk2 (zero-padding of the entry stream)
    hipMemsetAsync(ws + OFF_ADJ, 0, OFF_PK2 + SZ_PK2, stream);

    k_scatter<<<dim3(BATCH*NEDGE/256), dim3(256), 0, stream>>>(senders, recvs, adj, adjT);
    k_deg    <<<dim3(BATCH*NN/256),    dim3(256), 0, stream>>>(adj, adjT, degInv);
    k_build  <<<dim3(BATCH*NN/4),      dim3(256), 0, stream>>>(adj, adjT, degInv, n_node,
                                                               ents, vals, lens, pk2, lmax);
    k_lanczos<<<dim3(BATCH),           dim3(512), 0, stream>>>((const uint4*)pk2, lens, lam);
    k_prep32 <<<dim3(BATCH*NAUG),      dim3(256), 0, stream>>>(nodes, xf);

    // layer 0: spmm(xf) -> xt1; gemm(xf, xt1) -> crelu -> xf2 (xf layout)
    k_spmm  <<<dim3(NN/8, BATCH),      dim3(256), 0, stream>>>(ents, vals, lens, xf, lam, xt1);
    k_gemm32<<<dim3(DM/64, BATCH*16),  dim3(256), 0, stream>>>(xf, xt1, w00, w10, b00,
                                                               xf2, DM, NN*DM);
    // layer 1: spmm(xf2) -> xt1; gemm(xf2, xt1) -> crelu -> out ([b,512,512])
    k_spmm  <<<dim3(NN/8, BATCH),      dim3(256), 0, stream>>>(ents, vals, lens, xf2, lam, xt1);
    k_gemm32<<<dim3(DM/64, BATCH*16),  dim3(256), 0, stream>>>(xf2, xt1, w01, w11, b01,
                                                               out, 2*DM, DM);
}

// Round 14
// 1148.200 us; speedup vs baseline: 1.1186x; 1.1186x over previous
//
#include <hip/hip_runtime.h>
#include <stdint.h>

typedef unsigned long long u64;
typedef unsigned int u32;
typedef unsigned short u16;

#define BATCH 64
#define NN    512
#define NAUG  1024
#define DM    256
#define NEDGE 4096
#define CAP   64
#define PK2   32       // packed entry-pair slots = CAP/2 (written)
#define PK2A  36       // allocated slots (pad stays zero -> unguarded preload)
#define LM    128      // Lanczos steps (96 under-converged: R9 absmax 0.342)

// ---------------- workspace layout (bytes) ----------------
#define OFF_ADJ   ((size_t)0)
#define SZ_ADJ    ((size_t)BATCH*NN*8*8)                 // 2 MiB bitmask
#define OFF_ADJT  (OFF_ADJ + SZ_ADJ)
#define OFF_LAM   (OFF_ADJT + SZ_ADJ)                    // 4B lambda
#define OFF_LMX   (OFF_LAM + 64)                         // int lmax[64]
#define OFF_PK2   (OFF_LAM + 1024)
#define SZ_PK2    ((size_t)BATCH*PK2A*NN*16)             // 18.9 MB packed-pair lap stream
#define OFF_DEGI  (OFF_PK2 + SZ_PK2)
#define OFF_LENS  (OFF_DEGI + (size_t)BATCH*NN*4)
#define OFF_ENTS  (OFF_LENS + (size_t)BATCH*NN*4)
#define OFF_VALS  (OFF_ENTS + (size_t)BATCH*NN*CAP*4)
#define OFF_XF    (OFF_VALS + (size_t)BATCH*NN*CAP*4)    // x fp32 [b,1024,256]
#define OFF_XT1   (OFF_XF  + (size_t)BATCH*NAUG*DM*4)    // t1@x fp32
#define OFF_S     (OFF_XT1 + (size_t)BATCH*NAUG*DM*4)    // xf2 ping-pong (was sBuf)

// ---------------- adjacency scatter (bitmask) ----------------
__global__ void k_scatter(const int* __restrict__ senders, const int* __restrict__ receivers,
                          u64* __restrict__ adj, u64* __restrict__ adjT){
    int idx = blockIdx.x * 256 + threadIdx.x;          // BATCH*NEDGE threads
    int b = idx >> 12;
    int s = senders[idx];
    int r = receivers[idx];
    if (s >= 0){
        atomicOr(&adj [((size_t)b*NN + s)*8 + (r >> 6)], 1ull << (r & 63));
        atomicOr(&adjT[((size_t)b*NN + r)*8 + (s >> 6)], 1ull << (s & 63));
    }
}

// ---------------- degree (exact double 1/sqrt) ----------------
__global__ void k_deg(const u64* __restrict__ adj, const u64* __restrict__ adjT,
                      float* __restrict__ degInv){
    int idx = blockIdx.x * 256 + threadIdx.x;          // BATCH*NN threads
    const u64* a = adj  + (size_t)idx * 8;
    const u64* t = adjT + (size_t)idx * 8;
    int deg = 0;
#pragma unroll
    for (int w = 0; w < 8; ++w) deg += __popcll(a[w] | t[w]);
    degInv[idx] = (float)(1.0 / sqrt((double)(deg < 1 ? 1 : deg)));
}

// ---------------- build CSR + packed-pair stream (one wave per row) ----------
__global__ __launch_bounds__(256)
void k_build(const u64* __restrict__ adj, const u64* __restrict__ adjT,
             const float* __restrict__ degInv, const int* __restrict__ n_node,
             u32* __restrict__ ents, float* __restrict__ vals, int* __restrict__ lens,
             uint2* __restrict__ pk2, int* __restrict__ lmax){
    int gw   = (blockIdx.x * 256 + threadIdx.x) >> 6;  // global wave = row id
    int lane = threadIdx.x & 63;
    int b = gw >> 9;
    int i = gw & (NN - 1);
    const u64* arow = adj  + ((size_t)b*NN + i)*8;
    const u64* trow = adjT + ((size_t)b*NN + i)*8;
    int wsel = lane >> 3, sh = (lane & 7) * 8;
    u32 ba = (u32)((arow[wsel] >> sh) & 0xFFull);
    u32 bt = (u32)((trow[wsel] >> sh) & 0xFFull);
    int nn_b = n_node[b];
    bool mi  = i < nn_b;
    float di = degInv[b*NN + i];
    int j0 = lane * 8;

    float vr_[8], vi_[8];
    int cnt = 0;
#pragma unroll
    for (int jj = 0; jj < 8; ++jj){
        int j = j0 + jj;
        int a = (ba >> jj) & 1, t = (bt >> jj) & 1;
        bool mm = mi && (j < nn_b);
        float c = di * degInv[b*NN + j];
        float vr = 0.f, vi = 0.f;
        if (j == i){
            if (mm) vr = 1.0f - (a ? c : 0.0f);        // diag: mask*(1 - selfloop*c)
        } else if (mm && ((a | t) != 0)){
            if (a & t)      vr = -c;                   // lap = -c
            else if (a)     vi = -c;                   // lap = -i*c
            else            vi =  c;                   // lap = +i*c
        }
        vr_[jj] = vr; vi_[jj] = vi;
        cnt += (vr != 0.f || vi != 0.f) ? 1 : 0;
    }
    // wave-wide exclusive scan of cnt
    int off = cnt;
#pragma unroll
    for (int d = 1; d < 64; d <<= 1){
        int nb = __shfl_up(off, d);
        if (lane >= d) off += nb;
    }
    int excl = off - cnt;
    int tot  = __shfl(off, 63);
    int p = excl;
    u32*   erow = ents + ((size_t)b*NN + i)*CAP;
    float* vrow = vals + ((size_t)b*NN + i)*CAP;
#pragma unroll
    for (int jj = 0; jj < 8; ++jj){
        float vr = vr_[jj], vi = vi_[jj];
        if (vr != 0.f || vi != 0.f){
            if (p < CAP){
                int ty = (vi != 0.f) ? 1 : 0;
                int j = j0 + jj;
                float v = ty ? vi : vr;
                erow[p] = (u32)j | ((u32)ty << 9);
                vrow[p] = v;
                size_t slot = ((size_t)b*PK2A + (p >> 1))*NN + i;
                pk2[slot*2 + (p & 1)] =
                    make_uint2((u32)((j << 3) + (ty << 12)), __float_as_uint(v));
            }
            p++;
        }
    }
    if (lane == 63){
        int tc = tot > CAP ? CAP : tot;
        lens[b*NN + i] = tc;
        atomicMax(&lmax[b], tc);
    }
}

// ---------------- Lanczos: 8 waves/graph; SORTED row->lane assignment ----------
// (R16 version — verified passing; k_lanczos <247us after the sort.)
#define DO_G4(S0)                                                         \
    {                                                                     \
        float2 vva = VALS[S0][tid];                                       \
        float2 vvb = VALS[S0+1][tid];                                     \
        u32 opa = offp[S0], opb = offp[S0+1];                             \
        float2 u0 = *(const float2*)((const char*)XY + (opa & 0xFFFFu));  \
        float2 u1 = *(const float2*)((const char*)XY + (opa >> 16));      \
        float2 u2 = *(const float2*)((const char*)XY + (opb & 0xFFFFu));  \
        float2 u3 = *(const float2*)((const char*)XY + (opb >> 16));      \
        wr0 = fmaf(vva.x, u0.x, wr0); wi0 = fmaf(vva.x, u0.y, wi0);       \
        wr0 = fmaf(vva.y, u1.x, wr0); wi0 = fmaf(vva.y, u1.y, wi0);       \
        wr1 = fmaf(vvb.x, u2.x, wr1); wi1 = fmaf(vvb.x, u2.y, wi1);       \
        wr1 = fmaf(vvb.y, u3.x, wr1); wi1 = fmaf(vvb.y, u3.y, wi1);       \
        float2 vvc = VALS[S0+2][tid];                                     \
        float2 vvd = VALS[S0+3][tid];                                     \
        u32 opc = offp[S0+2], opd = offp[S0+3];                           \
        float2 u4 = *(const float2*)((const char*)XY + (opc & 0xFFFFu));  \
        float2 u5 = *(const float2*)((const char*)XY + (opc >> 16));      \
        float2 u6 = *(const float2*)((const char*)XY + (opd & 0xFFFFu));  \
        float2 u7 = *(const float2*)((const char*)XY + (opd >> 16));      \
        wr0 = fmaf(vvc.x, u4.x, wr0); wi0 = fmaf(vvc.x, u4.y, wi0);       \
        wr0 = fmaf(vvc.y, u5.x, wr0); wi0 = fmaf(vvc.y, u5.y, wi0);       \
        wr1 = fmaf(vvd.x, u6.x, wr1); wi1 = fmaf(vvd.x, u6.y, wi1);       \
        wr1 = fmaf(vvd.y, u7.x, wr1); wi1 = fmaf(vvd.y, u7.y, wi1);       \
    }

__global__ __launch_bounds__(512)
void k_lanczos(const uint4* __restrict__ pk2, const int* __restrict__ lens,
               float* __restrict__ lam){
    int b = blockIdx.x;
    int tid = threadIdx.x;
    int w = tid >> 6, l = tid & 63;
    __shared__ float2 XY[2*NN];                        // 8 KiB: X then Y
    __shared__ float2 VALS[PK2][NN];                   // 128 KiB: [slot][sorted-tid]
    __shared__ float alphS[LM], betS[LM];
    __shared__ float redA[8], redB[8];
    __shared__ int bCnt[PK2 + 1], bOff[PK2 + 1];       // ES buckets 0..32
    __shared__ u16 sortRow[NN];
    const uint4* base = pk2 + (size_t)b*PK2A*NN;

    // ---- counting sort: lane tid <- tid-th largest-ES row ----
    if (tid <= PK2) bCnt[tid] = 0;
    __syncthreads();
    int defES = (lens[b*NN + tid] + 1) >> 1;           // 0..32
    atomicAdd(&bCnt[defES], 1);
    __syncthreads();
    if (tid == 0){
        int acc = 0;
        for (int e = PK2; e >= 0; --e){ bOff[e] = acc; acc += bCnt[e]; }
    }
    __syncthreads();
    int pos = atomicAdd(&bOff[defES], 1);
    sortRow[pos] = (u16)tid;                           // thread at pos handles row tid
    __syncthreads();
    int row  = sortRow[tid];                           // my actual row
    int myES = (lens[b*NN + row] + 1) >> 1;

    // ---- preload: offsets packed into 32 regs, values staged to LDS ----
    u32 offp[PK2];
#pragma unroll
    for (int s = 0; s < PK2; ++s){
        uint4 q = base[(size_t)s*NN + row];
        offp[s] = (q.x & 0xFFFFu) | (q.z << 16);       // byteoff <= 8184, fits 13b
        VALS[s][tid] = make_float2(__uint_as_float(q.y), __uint_as_float(q.w));
    }

    u32 h = (u32)row * 2654435761u + 0x9E3779B9u;
    h ^= h >> 16; h *= 0x85EBCA6Bu; h ^= h >> 13;
    float xr = (float)(h & 0xFFFF) * (1.f/65536.f) - 0.5f;
    h = h * 1664525u + 1013904223u;
    float xi = (float)(h & 0xFFFF) * (1.f/65536.f) - 0.5f;
    float ss = xr*xr + xi*xi;
#pragma unroll
    for (int d = 1; d < 64; d <<= 1) ss += __shfl_xor(ss, d);
    if (l == 0) redA[w] = ss;
    __syncthreads();
    float inv0 = 1.f / sqrtf(redA[0] + redA[1] + redA[2] + redA[3]
                           + redA[4] + redA[5] + redA[6] + redA[7]);
    xr *= inv0; xi *= inv0;
    XY[row]      = make_float2(xr, xi);
    XY[NN + row] = make_float2(-xi, xr);
    __syncthreads();
    float v0r = 0.f, v0i = 0.f;
    float betaPrev = 0.f;
    int mEff = LM;
    for (int j = 0; j < LM; ++j){
        float wr0 = 0.f, wi0 = 0.f, wr1 = 0.f, wi1 = 0.f;
        if (myES >  0) DO_G4(0);
        if (myES >  4) DO_G4(4);
        if (myES >  8) DO_G4(8);
        if (myES > 12) DO_G4(12);
        if (myES > 16) DO_G4(16);
        if (myES > 20) DO_G4(20);
        if (myES > 24) DO_G4(24);
        if (myES > 28) DO_G4(28);
        float wr = wr0 + wr1, wi = wi0 + wi1;
        // alpha = Re<v1, w> : in-wave butterfly, then 8-way cross-wave via LDS
        float pa = xr*wr + xi*wi;
#pragma unroll
        for (int d = 1; d < 64; d <<= 1) pa += __shfl_xor(pa, d);
        if (l == 0) redA[w] = pa;
        __syncthreads();
        float paF = redA[0] + redA[1] + redA[2] + redA[3]
                  + redA[4] + redA[5] + redA[6] + redA[7];
        // w -= alpha*v1 + betaPrev*v0 ; beta = ||w|| (explicit, stable)
        wr -= paF*xr + betaPrev*v0r;
        wi -= paF*xi + betaPrev*v0i;
        float pb = wr*wr + wi*wi;
#pragma unroll
        for (int d = 1; d < 64; d <<= 1) pb += __shfl_xor(pb, d);
        if (l == 0) redB[w] = pb;
        __syncthreads();
        float pbF = redB[0] + redB[1] + redB[2] + redB[3]
                  + redB[4] + redB[5] + redB[6] + redB[7];
        float bta = sqrtf(pbF);
        if (w == 0 && l == 0){ alphS[j] = paF; betS[j] = bta; }
        if (pbF < 1e-14f){ mEff = j + 1; break; }      // uniform: pbF same all waves
        float binv = 1.f / bta;
        float nr = wr * binv;
        float ni = wi * binv;
        v0r = xr; v0i = xi;
        xr = nr; xi = ni;
        XY[row]      = make_float2(nr, ni);
        XY[NN + row] = make_float2(-ni, nr);
        __syncthreads();                               // X visible before next e-loop
        betaPrev = bta;
    }
    // parallel-midpoint Sturm bisection on wave 0: lane l tests mid_l; ballot.
    if (w == 0){
        int m = mEff;
        double lo = -0.5, hi = 2.5;                    // lap spectrum in [0,2]
        for (int sweep = 0; sweep < 5; ++sweep){
            double wd = (hi - lo) * (1.0/65.0);
            double mid = lo + wd * (double)(l + 1);
            int cnt = 0;
            double d = (double)alphS[0] - mid;
            if (d < 0.0) cnt++;
            for (int k = 1; k < m; ++k){
                if (d == 0.0) d = -1e-300;
                double bk = (double)betS[k-1];
                d = ((double)alphS[k] - mid) - bk*bk/d;
                if (d < 0.0) cnt++;
            }
            u64 mask = __ballot(cnt >= m);             // mid above lam_max
            if (mask == 0ull){
                lo = lo + wd * 64.0;
            } else {
                int L = __ffsll(mask) - 1;
                hi = lo + wd * (double)(L + 1);
                lo = lo + wd * (double)L;
            }
        }
        if (l == 0){
            float l1 = (float)hi;
            if (l1 < 0.f) l1 = 0.f;
            if (l1 > 2.0f) l1 = 2.0f;                  // normalized-lap bound
            atomicMax((u32*)lam, __float_as_uint(l1));
        }
    }
}

// ---------------- prep: xf = [nodes; 0] fp32 aug-node-major ----------------
__global__ void k_prep32(const float* __restrict__ nodes, float* __restrict__ xf){
    int row = blockIdx.x;                      // b*NAUG + i, 65536 blocks
    int t = threadIdx.x;
    int b = row >> 10, i = row & (NAUG - 1);
    float v = (i < NN) ? nodes[((size_t)b*NN + i)*DM + t] : 0.f;
    xf[(size_t)row*DM + t] = v;
}

// ---------------- SpMM: xt1 = (2/lam)*(lap @ x) - x, fp64 accum ----------------
// (R21 version restored — R22's 8-rows/block variant was ~57us/dispatch SLOWER:
// it cut TLP 8x and bloated registers; the tiny-block layout already hides
// gather latency with ~32 independent chains per CU.)
__global__ __launch_bounds__(256)
void k_spmm(const u32* __restrict__ ents, const float* __restrict__ vals,
            const int* __restrict__ lens, const float* __restrict__ xf,
            const float* __restrict__ lam, float* __restrict__ xt1){
    int i = blockIdx.x;                        // 0..511
    int b = blockIdx.y;
    int t = threadIdx.x;
    int len = lens[b*NN + i];
    const u32*   er = ents + ((size_t)b*NN + i)*CAP;
    const float* ev = vals + ((size_t)b*NN + i)*CAP;
    const float* xb = xf + (size_t)b*NAUG*DM;
    double ar = 0.0, ai = 0.0;
    for (int e = 0; e < len; ++e){
        u32 en = er[e];
        double v = (double)ev[e];
        int j = en & 511;
        double xr = (double)xb[(size_t)j*DM + t];
        double xi = (double)xb[(size_t)(NN + j)*DM + t];
        if (en & 512u){ ar = fma(v, -xi, ar); ai = fma(v, xr, ai); }
        else          { ar = fma(v,  xr, ar); ai = fma(v, xi, ai); }
    }
    double alpha = 2.0 / (double)lam[0];
    size_t ro = ((size_t)b*NAUG + i)*DM + t;
    size_t io = ((size_t)b*NAUG + NN + i)*DM + t;
    xt1[ro] = (float)(alpha*ar - (double)xf[ro]);
    xt1[io] = (float)(alpha*ai - (double)xf[io]);
}

// ---------------- fused GEMM+crelu: dst = crelu(x@w0 + xt1@w1 + bias) --------
// R23: R21 kernel + XCD-aware block remap. Default dispatch puts the 4
// n-blocks sharing one A row-tile on 4 DIFFERENT XCDs (round-robin) -> A
// (xf+xt1, 268MB) is re-fetched from HBM 4x (FETCH=265MB) and the ~900cy HBM
// latency sits in the staging barrier drain (VALUBusy 65%). Remap hw block id
// h = (by&7) | (bx<<3) | ((by>>3)<<5): all 4 bx of a row-tile share h%8 (same
// XCD) and are 8 apart in dispatch (temporally close) -> A L2-resident for 3
// of 4 reads. Pure index remap: per-output arithmetic untouched.
__global__ __launch_bounds__(256)
void k_gemm32(const float* __restrict__ A0, const float* __restrict__ xt1,
              const float* __restrict__ w0, const float* __restrict__ w1,
              const float* __restrict__ bias, float* __restrict__ dst,
              int rowStride, int imagOff){
    __shared__ float As[32][68];
    __shared__ float Bs[32][68];
    int h  = blockIdx.x;                       // flat 4096, XCD-swizzled
    int bx = (h >> 3) & 3;                     // n-block 0..3
    int by = ((h >> 5) << 3) | (h & 7);        // row-tile 0..1023
    int b  = by >> 4;
    int i0 = (by & 15) * 32;                   // 32 node-ids per tile
    int n0 = bx * 64;
    int tid = threadIdx.x;
    int tx = tid & 15, ty = tid >> 4;
    size_t abase = (size_t)b*NAUG*DM;
    double acc[4][4];
#pragma unroll
    for (int r = 0; r < 4; ++r)
#pragma unroll
        for (int c = 0; c < 4; ++c) acc[r][c] = 0.0;
    for (int ph = 0; ph < 2; ++ph){
        const float* A = ph ? xt1 : A0;
        const float* W = ph ? w1 : w0;
        for (int k0 = 0; k0 < DM; k0 += 32){
#pragma unroll
            for (int l = 0; l < 2; ++l){
                int fi = tid + l*256;          // 512 float4 slots each
                int m  = fi >> 3, c4 = fi & 7; // A: 64 tile-rows x 8 f4
                size_t grow = abase + (size_t)((m & 1)*NN + i0 + (m >> 1))*DM;
                float4 g = *(const float4*)(A + grow + k0 + c4*4);
                As[c4*4+0][m] = g.x; As[c4*4+1][m] = g.y;
                As[c4*4+2][m] = g.z; As[c4*4+3][m] = g.w;
                int kk = fi >> 4, n4 = fi & 15;// B: 32 k x 16 f4
                float4 hh = *(const float4*)(W + ((size_t)(k0 + kk))*DM + n0 + n4*4);
                *(float4*)&Bs[kk][n4*4] = hh;
            }
            __syncthreads();
            float facc[4][4];
#pragma unroll
            for (int r = 0; r < 4; ++r)
#pragma unroll
                for (int c = 0; c < 4; ++c) facc[r][c] = 0.f;
#pragma unroll
            for (int kk = 0; kk < 32; ++kk){
                float4 a4 = *(const float4*)&As[kk][ty*4];
                float4 b4 = *(const float4*)&Bs[kk][tx*4];
                facc[0][0] = fmaf(a4.x, b4.x, facc[0][0]);
                facc[0][1] = fmaf(a4.x, b4.y, facc[0][1]);
                facc[0][2] = fmaf(a4.x, b4.z, facc[0][2]);
                facc[0][3] = fmaf(a4.x, b4.w, facc[0][3]);
                facc[1][0] = fmaf(a4.y, b4.x, facc[1][0]);
                facc[1][1] = fmaf(a4.y, b4.y, facc[1][1]);
                facc[1][2] = fmaf(a4.y, b4.z, facc[1][2]);
                facc[1][3] = fmaf(a4.y, b4.w, facc[1][3]);
                facc[2][0] = fmaf(a4.z, b4.x, facc[2][0]);
                facc[2][1] = fmaf(a4.z, b4.y, facc[2][1]);
                facc[2][2] = fmaf(a4.z, b4.z, facc[2][2]);
                facc[2][3] = fmaf(a4.z, b4.w, facc[2][3]);
                facc[3][0] = fmaf(a4.w, b4.x, facc[3][0]);
                facc[3][1] = fmaf(a4.w, b4.y, facc[3][1]);
                facc[3][2] = fmaf(a4.w, b4.z, facc[3][2]);
                facc[3][3] = fmaf(a4.w, b4.w, facc[3][3]);
            }
#pragma unroll
            for (int r = 0; r < 4; ++r)
#pragma unroll
                for (int c = 0; c < 4; ++c) acc[r][c] += (double)facc[r][c];
            __syncthreads();
        }
    }
    // ---- epilogue: +bias, thread-local crelu on (re,im) row pairs, store ----
    float4 bi = *(const float4*)(bias + n0 + tx*4);
    float* outb = dst + (size_t)b*NAUG*DM;
#pragma unroll
    for (int q = 0; q < 2; ++q){
        float4 re, im;
        re.x = (float)(acc[q*2][0]   + (double)bi.x);
        re.y = (float)(acc[q*2][1]   + (double)bi.y);
        re.z = (float)(acc[q*2][2]   + (double)bi.z);
        re.w = (float)(acc[q*2][3]   + (double)bi.w);
        im.x = (float)(acc[q*2+1][0] + (double)bi.x);
        im.y = (float)(acc[q*2+1][1] + (double)bi.y);
        im.z = (float)(acc[q*2+1][2] + (double)bi.z);
        im.w = (float)(acc[q*2+1][3] + (double)bi.w);
        float4 gr, gi;
        gr.x = (re.x >= 0.f) ? re.x : 0.f;  gi.x = (re.x >= 0.f) ? im.x : 0.f;
        gr.y = (re.y >= 0.f) ? re.y : 0.f;  gi.y = (re.y >= 0.f) ? im.y : 0.f;
        gr.z = (re.z >= 0.f) ? re.z : 0.f;  gi.z = (re.z >= 0.f) ? im.z : 0.f;
        gr.w = (re.w >= 0.f) ? re.w : 0.f;  gi.w = (re.w >= 0.f) ? im.w : 0.f;
        int i = i0 + ty*2 + q;                 // node id for this pair
        float* pre = outb + (size_t)i*rowStride + n0 + tx*4;
        *(float4*)pre            = gr;
        *(float4*)(pre + imagOff) = gi;
    }
}

// ---------------- host launch ----------------
extern "C" void kernel_launch(void* const* d_in, const int* in_sizes, int n_in,
                              void* d_out, int out_size, void* d_ws, size_t ws_size,
                              hipStream_t stream){
    const float* nodes   = (const float*)d_in[0];
    const int*   senders = (const int*)  d_in[1];
    const int*   recvs   = (const int*)  d_in[2];
    const int*   n_node  = (const int*)  d_in[3];
    const float* w00     = (const float*)d_in[4];
    const float* b00     = (const float*)d_in[5];
    const float* w10     = (const float*)d_in[6];
    const float* w01     = (const float*)d_in[7];
    const float* b01     = (const float*)d_in[8];
    const float* w11     = (const float*)d_in[9];
    char* ws = (char*)d_ws;
    u64*   adj    = (u64*)  (ws + OFF_ADJ);
    u64*   adjT   = (u64*)  (ws + OFF_ADJT);
    float* lam    = (float*)(ws + OFF_LAM);
    int*   lmax   = (int*)  (ws + OFF_LMX);
    uint2* pk2    = (uint2*)(ws + OFF_PK2);
    float* degInv = (float*)(ws + OFF_DEGI);
    int*   lens   = (int*)  (ws + OFF_LENS);
    u32*   ents   = (u32*)  (ws + OFF_ENTS);
    float* vals   = (float*)(ws + OFF_VALS);
    float* xf     = (float*)(ws + OFF_XF);
    float* xt1    = (float*)(ws + OFF_XT1);
    float* xf2    = (float*)(ws + OFF_S);      // ping-pong layer-0 output
    float* out    = (float*)d_out;

    // zero adj bitmasks + lambda/lmax + pk2 (zero-padding of the entry stream)
    hipMemsetAsync(ws + OFF_ADJ, 0, OFF_PK2 + SZ_PK2, stream);

    k_scatter<<<dim3(BATCH*NEDGE/256), dim3(256), 0, stream>>>(senders, recvs, adj, adjT);
    k_deg    <<<dim3(BATCH*NN/256),    dim3(256), 0, stream>>>(adj, adjT, degInv);
    k_build  <<<dim3(BATCH*NN/4),      dim3(256), 0, stream>>>(adj, adjT, degInv, n_node,
                                                               ents, vals, lens, pk2, lmax);
    k_lanczos<<<dim3(BATCH),           dim3(512), 0, stream>>>((const uint4*)pk2, lens, lam);
    k_prep32 <<<dim3(BATCH*NAUG),      dim3(256), 0, stream>>>(nodes, xf);

    // layer 0: spmm(xf) -> xt1; gemm(xf, xt1) -> crelu -> xf2 (xf layout)
    k_spmm  <<<dim3(NN, BATCH),        dim3(256), 0, stream>>>(ents, vals, lens, xf, lam, xt1);
    k_gemm32<<<dim3(4096),             dim3(256), 0, stream>>>(xf, xt1, w00, w10, b00,
                                                               xf2, DM, NN*DM);
    // layer 1: spmm(xf2) -> xt1; gemm(xf2, xt1) -> crelu -> out ([b,512,512])
    k_spmm  <<<dim3(NN, BATCH),        dim3(256), 0, stream>>>(ents, vals, lens, xf2, lam, xt1);
    k_gemm32<<<dim3(4096),             dim3(256), 0, stream>>>(xf2, xt1, w01, w11, b01,
                                                               out, 2*DM, DM);
}

// Round 15
// 1140.484 us; speedup vs baseline: 1.1261x; 1.0068x over previous
//
#include <hip/hip_runtime.h>
#include <stdint.h>

typedef unsigned long long u64;
typedef unsigned int u32;
typedef unsigned short u16;

#define BATCH 64
#define NN    512
#define NAUG  1024
#define DM    256
#define NEDGE 4096
#define CAP   64
#define PK2   32       // packed entry-pair slots = CAP/2 (written)
#define PK2A  36       // allocated slots (pad stays zero -> unguarded preload)
#define LM    128      // Lanczos steps (96 under-converged: R9 absmax 0.342)

// ---------------- workspace layout (bytes) ----------------
#define OFF_ADJ   ((size_t)0)
#define SZ_ADJ    ((size_t)BATCH*NN*8*8)                 // 2 MiB bitmask
#define OFF_ADJT  (OFF_ADJ + SZ_ADJ)
#define OFF_LAM   (OFF_ADJT + SZ_ADJ)                    // 4B lambda
#define OFF_LMX   (OFF_LAM + 64)                         // int lmax[64]
#define OFF_PK2   (OFF_LAM + 1024)
#define SZ_PK2    ((size_t)BATCH*PK2A*NN*16)             // 18.9 MB packed-pair lap stream
#define OFF_DEGI  (OFF_PK2 + SZ_PK2)
#define OFF_LENS  (OFF_DEGI + (size_t)BATCH*NN*4)
#define OFF_ENTS  (OFF_LENS + (size_t)BATCH*NN*4)
#define OFF_VALS  (OFF_ENTS + (size_t)BATCH*NN*CAP*4)
#define OFF_XF    (OFF_VALS + (size_t)BATCH*NN*CAP*4)    // x fp32 [b,1024,256]
#define OFF_XT1   (OFF_XF  + (size_t)BATCH*NAUG*DM*4)    // t1@x fp32
#define OFF_S     (OFF_XT1 + (size_t)BATCH*NAUG*DM*4)    // xf2 ping-pong (was sBuf)

// ---------------- adjacency scatter (bitmask) ----------------
__global__ void k_scatter(const int* __restrict__ senders, const int* __restrict__ receivers,
                          u64* __restrict__ adj, u64* __restrict__ adjT){
    int idx = blockIdx.x * 256 + threadIdx.x;          // BATCH*NEDGE threads
    int b = idx >> 12;
    int s = senders[idx];
    int r = receivers[idx];
    if (s >= 0){
        atomicOr(&adj [((size_t)b*NN + s)*8 + (r >> 6)], 1ull << (r & 63));
        atomicOr(&adjT[((size_t)b*NN + r)*8 + (s >> 6)], 1ull << (s & 63));
    }
}

// ---------------- degree (exact double 1/sqrt) ----------------
__global__ void k_deg(const u64* __restrict__ adj, const u64* __restrict__ adjT,
                      float* __restrict__ degInv){
    int idx = blockIdx.x * 256 + threadIdx.x;          // BATCH*NN threads
    const u64* a = adj  + (size_t)idx * 8;
    const u64* t = adjT + (size_t)idx * 8;
    int deg = 0;
#pragma unroll
    for (int w = 0; w < 8; ++w) deg += __popcll(a[w] | t[w]);
    degInv[idx] = (float)(1.0 / sqrt((double)(deg < 1 ? 1 : deg)));
}

// ---------------- build CSR + packed-pair stream (one wave per row) ----------
__global__ __launch_bounds__(256)
void k_build(const u64* __restrict__ adj, const u64* __restrict__ adjT,
             const float* __restrict__ degInv, const int* __restrict__ n_node,
             u32* __restrict__ ents, float* __restrict__ vals, int* __restrict__ lens,
             uint2* __restrict__ pk2, int* __restrict__ lmax){
    int gw   = (blockIdx.x * 256 + threadIdx.x) >> 6;  // global wave = row id
    int lane = threadIdx.x & 63;
    int b = gw >> 9;
    int i = gw & (NN - 1);
    const u64* arow = adj  + ((size_t)b*NN + i)*8;
    const u64* trow = adjT + ((size_t)b*NN + i)*8;
    int wsel = lane >> 3, sh = (lane & 7) * 8;
    u32 ba = (u32)((arow[wsel] >> sh) & 0xFFull);
    u32 bt = (u32)((trow[wsel] >> sh) & 0xFFull);
    int nn_b = n_node[b];
    bool mi  = i < nn_b;
    float di = degInv[b*NN + i];
    int j0 = lane * 8;

    float vr_[8], vi_[8];
    int cnt = 0;
#pragma unroll
    for (int jj = 0; jj < 8; ++jj){
        int j = j0 + jj;
        int a = (ba >> jj) & 1, t = (bt >> jj) & 1;
        bool mm = mi && (j < nn_b);
        float c = di * degInv[b*NN + j];
        float vr = 0.f, vi = 0.f;
        if (j == i){
            if (mm) vr = 1.0f - (a ? c : 0.0f);        // diag: mask*(1 - selfloop*c)
        } else if (mm && ((a | t) != 0)){
            if (a & t)      vr = -c;                   // lap = -c
            else if (a)     vi = -c;                   // lap = -i*c
            else            vi =  c;                   // lap = +i*c
        }
        vr_[jj] = vr; vi_[jj] = vi;
        cnt += (vr != 0.f || vi != 0.f) ? 1 : 0;
    }
    // wave-wide exclusive scan of cnt
    int off = cnt;
#pragma unroll
    for (int d = 1; d < 64; d <<= 1){
        int nb = __shfl_up(off, d);
        if (lane >= d) off += nb;
    }
    int excl = off - cnt;
    int tot  = __shfl(off, 63);
    int p = excl;
    u32*   erow = ents + ((size_t)b*NN + i)*CAP;
    float* vrow = vals + ((size_t)b*NN + i)*CAP;
#pragma unroll
    for (int jj = 0; jj < 8; ++jj){
        float vr = vr_[jj], vi = vi_[jj];
        if (vr != 0.f || vi != 0.f){
            if (p < CAP){
                int ty = (vi != 0.f) ? 1 : 0;
                int j = j0 + jj;
                float v = ty ? vi : vr;
                erow[p] = (u32)j | ((u32)ty << 9);
                vrow[p] = v;
                size_t slot = ((size_t)b*PK2A + (p >> 1))*NN + i;
                pk2[slot*2 + (p & 1)] =
                    make_uint2((u32)((j << 3) + (ty << 12)), __float_as_uint(v));
            }
            p++;
        }
    }
    if (lane == 63){
        int tc = tot > CAP ? CAP : tot;
        lens[b*NN + i] = tc;
        atomicMax(&lmax[b], tc);
    }
}

// ---------------- Lanczos: 8 waves/graph; SORTED row->lane assignment ----------
// (R16 version — verified passing; k_lanczos <247us after the sort.)
#define DO_G4(S0)                                                         \
    {                                                                     \
        float2 vva = VALS[S0][tid];                                       \
        float2 vvb = VALS[S0+1][tid];                                     \
        u32 opa = offp[S0], opb = offp[S0+1];                             \
        float2 u0 = *(const float2*)((const char*)XY + (opa & 0xFFFFu));  \
        float2 u1 = *(const float2*)((const char*)XY + (opa >> 16));      \
        float2 u2 = *(const float2*)((const char*)XY + (opb & 0xFFFFu));  \
        float2 u3 = *(const float2*)((const char*)XY + (opb >> 16));      \
        wr0 = fmaf(vva.x, u0.x, wr0); wi0 = fmaf(vva.x, u0.y, wi0);       \
        wr0 = fmaf(vva.y, u1.x, wr0); wi0 = fmaf(vva.y, u1.y, wi0);       \
        wr1 = fmaf(vvb.x, u2.x, wr1); wi1 = fmaf(vvb.x, u2.y, wi1);       \
        wr1 = fmaf(vvb.y, u3.x, wr1); wi1 = fmaf(vvb.y, u3.y, wi1);       \
        float2 vvc = VALS[S0+2][tid];                                     \
        float2 vvd = VALS[S0+3][tid];                                     \
        u32 opc = offp[S0+2], opd = offp[S0+3];                           \
        float2 u4 = *(const float2*)((const char*)XY + (opc & 0xFFFFu));  \
        float2 u5 = *(const float2*)((const char*)XY + (opc >> 16));      \
        float2 u6 = *(const float2*)((const char*)XY + (opd & 0xFFFFu));  \
        float2 u7 = *(const float2*)((const char*)XY + (opd >> 16));      \
        wr0 = fmaf(vvc.x, u4.x, wr0); wi0 = fmaf(vvc.x, u4.y, wi0);       \
        wr0 = fmaf(vvc.y, u5.x, wr0); wi0 = fmaf(vvc.y, u5.y, wi0);       \
        wr1 = fmaf(vvd.x, u6.x, wr1); wi1 = fmaf(vvd.x, u6.y, wi1);       \
        wr1 = fmaf(vvd.y, u7.x, wr1); wi1 = fmaf(vvd.y, u7.y, wi1);       \
    }

__global__ __launch_bounds__(512)
void k_lanczos(const uint4* __restrict__ pk2, const int* __restrict__ lens,
               float* __restrict__ lam){
    int b = blockIdx.x;
    int tid = threadIdx.x;
    int w = tid >> 6, l = tid & 63;
    __shared__ float2 XY[2*NN];                        // 8 KiB: X then Y
    __shared__ float2 VALS[PK2][NN];                   // 128 KiB: [slot][sorted-tid]
    __shared__ float alphS[LM], betS[LM];
    __shared__ float redA[8], redB[8];
    __shared__ int bCnt[PK2 + 1], bOff[PK2 + 1];       // ES buckets 0..32
    __shared__ u16 sortRow[NN];
    const uint4* base = pk2 + (size_t)b*PK2A*NN;

    // ---- counting sort: lane tid <- tid-th largest-ES row ----
    if (tid <= PK2) bCnt[tid] = 0;
    __syncthreads();
    int defES = (lens[b*NN + tid] + 1) >> 1;           // 0..32
    atomicAdd(&bCnt[defES], 1);
    __syncthreads();
    if (tid == 0){
        int acc = 0;
        for (int e = PK2; e >= 0; --e){ bOff[e] = acc; acc += bCnt[e]; }
    }
    __syncthreads();
    int pos = atomicAdd(&bOff[defES], 1);
    sortRow[pos] = (u16)tid;                           // thread at pos handles row tid
    __syncthreads();
    int row  = sortRow[tid];                           // my actual row
    int myES = (lens[b*NN + row] + 1) >> 1;

    // ---- preload: offsets packed into 32 regs, values staged to LDS ----
    u32 offp[PK2];
#pragma unroll
    for (int s = 0; s < PK2; ++s){
        uint4 q = base[(size_t)s*NN + row];
        offp[s] = (q.x & 0xFFFFu) | (q.z << 16);       // byteoff <= 8184, fits 13b
        VALS[s][tid] = make_float2(__uint_as_float(q.y), __uint_as_float(q.w));
    }

    u32 h = (u32)row * 2654435761u + 0x9E3779B9u;
    h ^= h >> 16; h *= 0x85EBCA6Bu; h ^= h >> 13;
    float xr = (float)(h & 0xFFFF) * (1.f/65536.f) - 0.5f;
    h = h * 1664525u + 1013904223u;
    float xi = (float)(h & 0xFFFF) * (1.f/65536.f) - 0.5f;
    float ss = xr*xr + xi*xi;
#pragma unroll
    for (int d = 1; d < 64; d <<= 1) ss += __shfl_xor(ss, d);
    if (l == 0) redA[w] = ss;
    __syncthreads();
    float inv0 = 1.f / sqrtf(redA[0] + redA[1] + redA[2] + redA[3]
                           + redA[4] + redA[5] + redA[6] + redA[7]);
    xr *= inv0; xi *= inv0;
    XY[row]      = make_float2(xr, xi);
    XY[NN + row] = make_float2(-xi, xr);
    __syncthreads();
    float v0r = 0.f, v0i = 0.f;
    float betaPrev = 0.f;
    int mEff = LM;
    for (int j = 0; j < LM; ++j){
        float wr0 = 0.f, wi0 = 0.f, wr1 = 0.f, wi1 = 0.f;
        if (myES >  0) DO_G4(0);
        if (myES >  4) DO_G4(4);
        if (myES >  8) DO_G4(8);
        if (myES > 12) DO_G4(12);
        if (myES > 16) DO_G4(16);
        if (myES > 20) DO_G4(20);
        if (myES > 24) DO_G4(24);
        if (myES > 28) DO_G4(28);
        float wr = wr0 + wr1, wi = wi0 + wi1;
        // alpha = Re<v1, w> : in-wave butterfly, then 8-way cross-wave via LDS
        float pa = xr*wr + xi*wi;
#pragma unroll
        for (int d = 1; d < 64; d <<= 1) pa += __shfl_xor(pa, d);
        if (l == 0) redA[w] = pa;
        __syncthreads();
        float paF = redA[0] + redA[1] + redA[2] + redA[3]
                  + redA[4] + redA[5] + redA[6] + redA[7];
        // w -= alpha*v1 + betaPrev*v0 ; beta = ||w|| (explicit, stable)
        wr -= paF*xr + betaPrev*v0r;
        wi -= paF*xi + betaPrev*v0i;
        float pb = wr*wr + wi*wi;
#pragma unroll
        for (int d = 1; d < 64; d <<= 1) pb += __shfl_xor(pb, d);
        if (l == 0) redB[w] = pb;
        __syncthreads();
        float pbF = redB[0] + redB[1] + redB[2] + redB[3]
                  + redB[4] + redB[5] + redB[6] + redB[7];
        float bta = sqrtf(pbF);
        if (w == 0 && l == 0){ alphS[j] = paF; betS[j] = bta; }
        if (pbF < 1e-14f){ mEff = j + 1; break; }      // uniform: pbF same all waves
        float binv = 1.f / bta;
        float nr = wr * binv;
        float ni = wi * binv;
        v0r = xr; v0i = xi;
        xr = nr; xi = ni;
        XY[row]      = make_float2(nr, ni);
        XY[NN + row] = make_float2(-ni, nr);
        __syncthreads();                               // X visible before next e-loop
        betaPrev = bta;
    }
    // parallel-midpoint Sturm bisection on wave 0: lane l tests mid_l; ballot.
    if (w == 0){
        int m = mEff;
        double lo = -0.5, hi = 2.5;                    // lap spectrum in [0,2]
        for (int sweep = 0; sweep < 5; ++sweep){
            double wd = (hi - lo) * (1.0/65.0);
            double mid = lo + wd * (double)(l + 1);
            int cnt = 0;
            double d = (double)alphS[0] - mid;
            if (d < 0.0) cnt++;
            for (int k = 1; k < m; ++k){
                if (d == 0.0) d = -1e-300;
                double bk = (double)betS[k-1];
                d = ((double)alphS[k] - mid) - bk*bk/d;
                if (d < 0.0) cnt++;
            }
            u64 mask = __ballot(cnt >= m);             // mid above lam_max
            if (mask == 0ull){
                lo = lo + wd * 64.0;
            } else {
                int L = __ffsll(mask) - 1;
                hi = lo + wd * (double)(L + 1);
                lo = lo + wd * (double)L;
            }
        }
        if (l == 0){
            float l1 = (float)hi;
            if (l1 < 0.f) l1 = 0.f;
            if (l1 > 2.0f) l1 = 2.0f;                  // normalized-lap bound
            atomicMax((u32*)lam, __float_as_uint(l1));
        }
    }
}

// ---------------- prep: xf = [nodes; 0] fp32 aug-node-major ----------------
__global__ void k_prep32(const float* __restrict__ nodes, float* __restrict__ xf){
    int row = blockIdx.x;                      // b*NAUG + i, 65536 blocks
    int t = threadIdx.x;
    int b = row >> 10, i = row & (NAUG - 1);
    float v = (i < NN) ? nodes[((size_t)b*NN + i)*DM + t] : 0.f;
    xf[(size_t)row*DM + t] = v;
}

// ---------------- SpMM: xt1 = (2/lam)*(lap @ x) - x, fp64 accum ----------------
// (R21 version — verified; R22's 8-rows/block variant was slower.)
__global__ __launch_bounds__(256)
void k_spmm(const u32* __restrict__ ents, const float* __restrict__ vals,
            const int* __restrict__ lens, const float* __restrict__ xf,
            const float* __restrict__ lam, float* __restrict__ xt1){
    int i = blockIdx.x;                        // 0..511
    int b = blockIdx.y;
    int t = threadIdx.x;
    int len = lens[b*NN + i];
    const u32*   er = ents + ((size_t)b*NN + i)*CAP;
    const float* ev = vals + ((size_t)b*NN + i)*CAP;
    const float* xb = xf + (size_t)b*NAUG*DM;
    double ar = 0.0, ai = 0.0;
    for (int e = 0; e < len; ++e){
        u32 en = er[e];
        double v = (double)ev[e];
        int j = en & 511;
        double xr = (double)xb[(size_t)j*DM + t];
        double xi = (double)xb[(size_t)(NN + j)*DM + t];
        if (en & 512u){ ar = fma(v, -xi, ar); ai = fma(v, xr, ai); }
        else          { ar = fma(v,  xr, ar); ai = fma(v, xi, ai); }
    }
    double alpha = 2.0 / (double)lam[0];
    size_t ro = ((size_t)b*NAUG + i)*DM + t;
    size_t io = ((size_t)b*NAUG + NN + i)*DM + t;
    xt1[ro] = (float)(alpha*ar - (double)xf[ro]);
    xt1[io] = (float)(alpha*ai - (double)xf[io]);
}

// ---------------- fused GEMM+crelu: dst = crelu(x@w0 + xt1@w1 + bias) --------
// R24 = R23 + A-stage XOR column swizzle. R23 proved gemm is NOT memory-bound
// (FETCH 265->68MB, time flat); remaining counter lead: 12.58M LDS bank
// conflicts from the A-transpose scalar writes (lanes 0-7 at banks {0,16} ->
// 4-way on 8 writes/kstep). Swizzle: phys_col4 = col4 ^ (row>>2) — writes land
// on banks 20*c4 mod 32 (distinct per 8-lane group, uniform 2-way over the
// wave = free per m136); reads become 4 unique 16B addrs x16 broadcast
// (conflict-free); kk is compile-time so the XOR folds into immediates.
// Pure LDS layout change: all arithmetic bit-identical (R17 errata).
__global__ __launch_bounds__(256)
void k_gemm32(const float* __restrict__ A0, const float* __restrict__ xt1,
              const float* __restrict__ w0, const float* __restrict__ w1,
              const float* __restrict__ bias, float* __restrict__ dst,
              int rowStride, int imagOff){
    __shared__ float As[32][68];
    __shared__ float Bs[32][68];
    int h  = blockIdx.x;                       // flat 4096, XCD-swizzled
    int bx = (h >> 3) & 3;                     // n-block 0..3
    int by = ((h >> 5) << 3) | (h & 7);        // row-tile 0..1023
    int b  = by >> 4;
    int i0 = (by & 15) * 32;                   // 32 node-ids per tile
    int n0 = bx * 64;
    int tid = threadIdx.x;
    int tx = tid & 15, ty = tid >> 4;
    size_t abase = (size_t)b*NAUG*DM;
    double acc[4][4];
#pragma unroll
    for (int r = 0; r < 4; ++r)
#pragma unroll
        for (int c = 0; c < 4; ++c) acc[r][c] = 0.0;
    for (int ph = 0; ph < 2; ++ph){
        const float* A = ph ? xt1 : A0;
        const float* W = ph ? w1 : w0;
        for (int k0 = 0; k0 < DM; k0 += 32){
#pragma unroll
            for (int l = 0; l < 2; ++l){
                int fi = tid + l*256;          // 512 float4 slots each
                int m  = fi >> 3, c4 = fi & 7; // A: 64 tile-rows x 8 f4
                size_t grow = abase + (size_t)((m & 1)*NN + i0 + (m >> 1))*DM;
                float4 g = *(const float4*)(A + grow + k0 + c4*4);
                int pc = ((((m >> 2) ^ c4) << 2) | (m & 3));   // swizzled column
                As[c4*4+0][pc] = g.x; As[c4*4+1][pc] = g.y;
                As[c4*4+2][pc] = g.z; As[c4*4+3][pc] = g.w;
                int kk = fi >> 4, n4 = fi & 15;// B: 32 k x 16 f4
                float4 hh = *(const float4*)(W + ((size_t)(k0 + kk))*DM + n0 + n4*4);
                *(float4*)&Bs[kk][n4*4] = hh;
            }
            __syncthreads();
            float facc[4][4];
#pragma unroll
            for (int r = 0; r < 4; ++r)
#pragma unroll
                for (int c = 0; c < 4; ++c) facc[r][c] = 0.f;
#pragma unroll
            for (int kk = 0; kk < 32; ++kk){
                float4 a4 = *(const float4*)&As[kk][((ty ^ ((kk >> 2) & 7)) << 2)];
                float4 b4 = *(const float4*)&Bs[kk][tx*4];
                facc[0][0] = fmaf(a4.x, b4.x, facc[0][0]);
                facc[0][1] = fmaf(a4.x, b4.y, facc[0][1]);
                facc[0][2] = fmaf(a4.x, b4.z, facc[0][2]);
                facc[0][3] = fmaf(a4.x, b4.w, facc[0][3]);
                facc[1][0] = fmaf(a4.y, b4.x, facc[1][0]);
                facc[1][1] = fmaf(a4.y, b4.y, facc[1][1]);
                facc[1][2] = fmaf(a4.y, b4.z, facc[1][2]);
                facc[1][3] = fmaf(a4.y, b4.w, facc[1][3]);
                facc[2][0] = fmaf(a4.z, b4.x, facc[2][0]);
                facc[2][1] = fmaf(a4.z, b4.y, facc[2][1]);
                facc[2][2] = fmaf(a4.z, b4.z, facc[2][2]);
                facc[2][3] = fmaf(a4.z, b4.w, facc[2][3]);
                facc[3][0] = fmaf(a4.w, b4.x, facc[3][0]);
                facc[3][1] = fmaf(a4.w, b4.y, facc[3][1]);
                facc[3][2] = fmaf(a4.w, b4.z, facc[3][2]);
                facc[3][3] = fmaf(a4.w, b4.w, facc[3][3]);
            }
#pragma unroll
            for (int r = 0; r < 4; ++r)
#pragma unroll
                for (int c = 0; c < 4; ++c) acc[r][c] += (double)facc[r][c];
            __syncthreads();
        }
    }
    // ---- epilogue: +bias, thread-local crelu on (re,im) row pairs, store ----
    float4 bi = *(const float4*)(bias + n0 + tx*4);
    float* outb = dst + (size_t)b*NAUG*DM;
#pragma unroll
    for (int q = 0; q < 2; ++q){
        float4 re, im;
        re.x = (float)(acc[q*2][0]   + (double)bi.x);
        re.y = (float)(acc[q*2][1]   + (double)bi.y);
        re.z = (float)(acc[q*2][2]   + (double)bi.z);
        re.w = (float)(acc[q*2][3]   + (double)bi.w);
        im.x = (float)(acc[q*2+1][0] + (double)bi.x);
        im.y = (float)(acc[q*2+1][1] + (double)bi.y);
        im.z = (float)(acc[q*2+1][2] + (double)bi.z);
        im.w = (float)(acc[q*2+1][3] + (double)bi.w);
        float4 gr, gi;
        gr.x = (re.x >= 0.f) ? re.x : 0.f;  gi.x = (re.x >= 0.f) ? im.x : 0.f;
        gr.y = (re.y >= 0.f) ? re.y : 0.f;  gi.y = (re.y >= 0.f) ? im.y : 0.f;
        gr.z = (re.z >= 0.f) ? re.z : 0.f;  gi.z = (re.z >= 0.f) ? im.z : 0.f;
        gr.w = (re.w >= 0.f) ? re.w : 0.f;  gi.w = (re.w >= 0.f) ? im.w : 0.f;
        int i = i0 + ty*2 + q;                 // node id for this pair
        float* pre = outb + (size_t)i*rowStride + n0 + tx*4;
        *(float4*)pre            = gr;
        *(float4*)(pre + imagOff) = gi;
    }
}

// ---------------- host launch ----------------
extern "C" void kernel_launch(void* const* d_in, const int* in_sizes, int n_in,
                              void* d_out, int out_size, void* d_ws, size_t ws_size,
                              hipStream_t stream){
    const float* nodes   = (const float*)d_in[0];
    const int*   senders = (const int*)  d_in[1];
    const int*   recvs   = (const int*)  d_in[2];
    const int*   n_node  = (const int*)  d_in[3];
    const float* w00     = (const float*)d_in[4];
    const float* b00     = (const float*)d_in[5];
    const float* w10     = (const float*)d_in[6];
    const float* w01     = (const float*)d_in[7];
    const float* b01     = (const float*)d_in[8];
    const float* w11     = (const float*)d_in[9];
    char* ws = (char*)d_ws;
    u64*   adj    = (u64*)  (ws + OFF_ADJ);
    u64*   adjT   = (u64*)  (ws + OFF_ADJT);
    float* lam    = (float*)(ws + OFF_LAM);
    int*   lmax   = (int*)  (ws + OFF_LMX);
    uint2* pk2    = (uint2*)(ws + OFF_PK2);
    float* degInv = (float*)(ws + OFF_DEGI);
    int*   lens   = (int*)  (ws + OFF_LENS);
    u32*   ents   = (u32*)  (ws + OFF_ENTS);
    float* vals   = (float*)(ws + OFF_VALS);
    float* xf     = (float*)(ws + OFF_XF);
    float* xt1    = (float*)(ws + OFF_XT1);
    float* xf2    = (float*)(ws + OFF_S);      // ping-pong layer-0 output
    float* out    = (float*)d_out;

    // zero adj bitmasks + lambda/lmax + pk2 (zero-padding of the entry stream)
    hipMemsetAsync(ws + OFF_ADJ, 0, OFF_PK2 + SZ_PK2, stream);

    k_scatter<<<dim3(BATCH*NEDGE/256), dim3(256), 0, stream>>>(senders, recvs, adj, adjT);
    k_deg    <<<dim3(BATCH*NN/256),    dim3(256), 0, stream>>>(adj, adjT, degInv);
    k_build  <<<dim3(BATCH*NN/4),      dim3(256), 0, stream>>>(adj, adjT, degInv, n_node,
                                                               ents, vals, lens, pk2, lmax);
    k_lanczos<<<dim3(BATCH),           dim3(512), 0, stream>>>((const uint4*)pk2, lens, lam);
    k_prep32 <<<dim3(BATCH*NAUG),      dim3(256), 0, stream>>>(nodes, xf);

    // layer 0: spmm(xf) -> xt1; gemm(xf, xt1) -> crelu -> xf2 (xf layout)
    k_spmm  <<<dim3(NN, BATCH),        dim3(256), 0, stream>>>(ents, vals, lens, xf, lam, xt1);
    k_gemm32<<<dim3(4096),             dim3(256), 0, stream>>>(xf, xt1, w00, w10, b00,
                                                               xf2, DM, NN*DM);
    // layer 1: spmm(xf2) -> xt1; gemm(xf2, xt1) -> crelu -> out ([b,512,512])
    k_spmm  <<<dim3(NN, BATCH),        dim3(256), 0, stream>>>(ents, vals, lens, xf2, lam, xt1);
    k_gemm32<<<dim3(4096),             dim3(256), 0, stream>>>(xf2, xt1, w01, w11, b01,
                                                               out, 2*DM, DM);
}